// Round 4
// baseline (132.030 us; speedup 1.0000x reference)
//
#include <hip/hip_runtime.h>

#define BB 16384
#define AA 512
#define NBLK 2048            // 2048 blocks x 4 waves x 2 rows = 16384 rows
#define WAVES 4
#define ROWS_PER_WAVE 2

__device__ __forceinline__ void ann_loss(float pp0, float pp1, int lab, float ww,
                                         float& sum, bool& anyv) {
    const float m0 = fmaxf(pp0, 0.0f);
    const float e0 = __logf(1.0f + __expf(-fabsf(pp0)));
    const float m1 = fmaxf(pp1, 0.0f);
    const float e1 = __logf(1.0f + __expf(-fabsf(pp1)));
    // t=1: 0.5*(softplus(p0) + w*softplus(-p1))
    // t=0: 0.5*(w*softplus(-p0) + softplus(p1))
    const float pa = (lab == 1)
        ? 0.5f * ((m0 + e0) + ww * ((m1 - pp1) + e1))
        : 0.5f * (ww * ((m0 - pp0) + e0) + (m1 + e1));
    if (lab != -1) { sum += pa; anyv = true; }
}

extern "C" __global__ void __launch_bounds__(256, 4)
mtl_fused(const float* __restrict__ preds, const int* __restrict__ labels,
          const float* __restrict__ weights,
          unsigned long long* __restrict__ part,   // [NBLK] packed (cnt<<32 | sum)
          unsigned int* __restrict__ counter,
          float* __restrict__ out) {
    const int tid  = threadIdx.x;
    const int wv   = tid >> 6;
    const int lane = tid & 63;
    const int gw   = blockIdx.x * WAVES + wv;
    const int row0 = gw * ROWS_PER_WAVE;

    const float* prow0 = preds  + (size_t)row0 * (AA * 2);
    const float* prow1 = prow0 + (AA * 2);
    const int*   lrow0 = labels + (size_t)row0 * AA;
    const int*   lrow1 = lrow0 + AA;

    // Hoist ALL loads: 8 float4 preds + 8 int2 labels + 4 float2 weights
    // (weights shared across both rows) = 20 loads in flight per lane.
    float4 p0[4], p1[4];
    int2   l0[4], l1[4];
    float2 w[4];
    #pragma unroll
    for (int k = 0; k < 4; ++k) {
        const int c = lane + (k << 6);           // float4-chunk 0..255
        p0[k] = *reinterpret_cast<const float4*>(prow0 + (size_t)c * 4);
        p1[k] = *reinterpret_cast<const float4*>(prow1 + (size_t)c * 4);
        l0[k] = *reinterpret_cast<const int2*>(lrow0 + (size_t)c * 2);
        l1[k] = *reinterpret_cast<const int2*>(lrow1 + (size_t)c * 2);
        w[k]  = *reinterpret_cast<const float2*>(weights + (size_t)c * 2);
    }

    float sum = 0.0f;
    float cnt = 0.0f;
    bool anyv0 = false, anyv1 = false;
    #pragma unroll
    for (int k = 0; k < 4; ++k) {
        ann_loss(p0[k].x, p0[k].y, l0[k].x, w[k].x, sum, anyv0);
        ann_loss(p0[k].z, p0[k].w, l0[k].y, w[k].y, sum, anyv0);
        ann_loss(p1[k].x, p1[k].y, l1[k].x, w[k].x, sum, anyv1);
        ann_loss(p1[k].z, p1[k].w, l1[k].y, w[k].y, sum, anyv1);
    }
    cnt += (__ballot(anyv0) != 0ULL) ? 1.0f : 0.0f;
    cnt += (__ballot(anyv1) != 0ULL) ? 1.0f : 0.0f;

    #pragma unroll
    for (int off = 32; off > 0; off >>= 1) sum += __shfl_down(sum, off);
    // cnt is wave-uniform (ballot), no reduce needed

    __shared__ float2 sl[4];
    __shared__ bool   amLast;
    if (lane == 0) sl[wv] = make_float2(sum, cnt);
    __syncthreads();
    if (tid == 0) {
        const float2 a = sl[0], b = sl[1], c2 = sl[2], d = sl[3];
        const float S = a.x + b.x + c2.x + d.x;
        const float C = a.y + b.y + c2.y + d.y;
        const unsigned long long packed =
            ((unsigned long long)__float_as_uint(C) << 32) | __float_as_uint(S);
        __hip_atomic_store(&part[blockIdx.x], packed,
                           __ATOMIC_RELEASE, __HIP_MEMORY_SCOPE_AGENT);
        const unsigned prev = __hip_atomic_fetch_add(counter, 1u,
                           __ATOMIC_ACQ_REL, __HIP_MEMORY_SCOPE_AGENT);
        amLast = (prev == NBLK - 1);
    }
    __syncthreads();

    if (amLast) {
        float s = 0.0f, c = 0.0f;
        #pragma unroll
        for (int k = 0; k < NBLK / 256; ++k) {
            const unsigned long long v = __hip_atomic_load(&part[tid + (k << 8)],
                               __ATOMIC_RELAXED, __HIP_MEMORY_SCOPE_AGENT);
            s += __uint_as_float((unsigned)(v & 0xffffffffu));
            c += __uint_as_float((unsigned)(v >> 32));
        }
        #pragma unroll
        for (int off = 32; off > 0; off >>= 1) {
            s += __shfl_down(s, off);
            c += __shfl_down(c, off);
        }
        __shared__ float s2[4], c2a[4];
        if (lane == 0) { s2[wv] = s; c2a[wv] = c; }
        __syncthreads();
        if (tid == 0) {
            const float S = s2[0] + s2[1] + s2[2] + s2[3];
            const float C = c2a[0] + c2a[1] + c2a[2] + c2a[3];
            out[0] = S / fmaxf(C, 1.0f);
        }
    }
}

extern "C" void kernel_launch(void* const* d_in, const int* in_sizes, int n_in,
                              void* d_out, int out_size, void* d_ws, size_t ws_size,
                              hipStream_t stream) {
    const float* preds   = (const float*)d_in[0];
    const int*   labels  = (const int*)d_in[1];
    const float* weights = (const float*)d_in[2];
    float*       out     = (float*)d_out;

    unsigned int*       counter = (unsigned int*)d_ws;                 // 4 B @ 0
    unsigned long long* part    = (unsigned long long*)((char*)d_ws + 128);

    hipMemsetAsync(counter, 0, sizeof(unsigned int), stream);
    mtl_fused<<<NBLK, 256, 0, stream>>>(preds, labels, weights, part, counter, out);
}

// Round 5
// 23.169 us; speedup vs baseline: 5.6987x; 5.6987x over previous
//
#include <hip/hip_runtime.h>

#define BB 16384
#define AA 512
#define NBLK 2048            // 2048 blocks x 4 waves x 2 rows = 16384 rows
#define WAVES 4
#define ROWS_PER_WAVE 2

// One annotation pair (2 preds, 1 label, 1 weight) -> masked elem-mean loss.
__device__ __forceinline__ float ann_pair(float pp0, float pp1, int lab, float ww,
                                          bool& anyv) {
    const float m0 = fmaxf(pp0, 0.0f);
    const float e0 = __logf(1.0f + __expf(-fabsf(pp0)));
    const float m1 = fmaxf(pp1, 0.0f);
    const float e1 = __logf(1.0f + __expf(-fabsf(pp1)));
    // t=1: 0.5*(softplus(p0) + w*softplus(-p1))
    // t=0: 0.5*(w*softplus(-p0) + softplus(p1))
    const float pa = (lab == 1)
        ? 0.5f * ((m0 + e0) + ww * ((m1 - pp1) + e1))
        : 0.5f * (ww * ((m0 - pp0) + e0) + (m1 + e1));
    const bool v = (lab != -1);
    anyv |= v;
    return v ? pa : 0.0f;
}

// One 64-lane wave per 2 consecutive rows. Each lane owns 4 consecutive
// annotations per chunk, 2 chunks per row: all loads are 16 B/lane
// (float4/int4), weights loaded once and shared across both rows.
// 14 VMEM loads per lane total (vs 24 in the prior version).
extern "C" __global__ void __launch_bounds__(256, 8)
mtl_partial(const float* __restrict__ preds, const int* __restrict__ labels,
            const float* __restrict__ weights, float2* __restrict__ part) {
    const int tid  = threadIdx.x;
    const int wv   = tid >> 6;
    const int lane = tid & 63;
    const int gw   = blockIdx.x * WAVES + wv;
    const int row0 = gw * ROWS_PER_WAVE;

    // weights for this lane's 8 annotations (4 per chunk), shared by both rows
    const float4* w4 = reinterpret_cast<const float4*>(weights);
    const float4 wA = w4[lane];        // ann 4*lane   .. 4*lane+3
    const float4 wB = w4[lane + 64];   // ann 4*lane+256 ..

    float sum = 0.0f;
    float cnt = 0.0f;

    #pragma unroll
    for (int r = 0; r < ROWS_PER_WAVE; ++r) {
        const int row = row0 + r;
        const float4* pr = reinterpret_cast<const float4*>(preds + (size_t)row * (AA * 2));
        const int4*   lr = reinterpret_cast<const int4*>(labels + (size_t)row * AA);

        bool anyv = false;

        // chunk A: annotations 4*lane .. 4*lane+3
        {
            const float4 pa0 = pr[lane * 2];
            const float4 pa1 = pr[lane * 2 + 1];
            const int4   l   = lr[lane];
            sum += ann_pair(pa0.x, pa0.y, l.x, wA.x, anyv);
            sum += ann_pair(pa0.z, pa0.w, l.y, wA.y, anyv);
            sum += ann_pair(pa1.x, pa1.y, l.z, wA.z, anyv);
            sum += ann_pair(pa1.z, pa1.w, l.w, wA.w, anyv);
        }
        // chunk B: annotations 4*(lane+64) .. +3
        {
            const float4 pb0 = pr[(lane + 64) * 2];
            const float4 pb1 = pr[(lane + 64) * 2 + 1];
            const int4   l   = lr[lane + 64];
            sum += ann_pair(pb0.x, pb0.y, l.x, wB.x, anyv);
            sum += ann_pair(pb0.z, pb0.w, l.y, wB.y, anyv);
            sum += ann_pair(pb1.x, pb1.y, l.z, wB.z, anyv);
            sum += ann_pair(pb1.z, pb1.w, l.w, wB.w, anyv);
        }

        // all-invalid rows contribute 0 to sum; only has_valid needed
        cnt += (__ballot(anyv) != 0ULL) ? 1.0f : 0.0f;
    }

    #pragma unroll
    for (int off = 32; off > 0; off >>= 1) sum += __shfl_down(sum, off);
    // cnt is wave-uniform (ballot), no reduce needed

    __shared__ float2 sl[4];
    if (lane == 0) sl[wv] = make_float2(sum, cnt);
    __syncthreads();
    if (tid == 0) {
        const float2 a = sl[0], b = sl[1], c = sl[2], d = sl[3];
        part[blockIdx.x] = make_float2(a.x + b.x + c.x + d.x,
                                       a.y + b.y + c.y + d.y);
    }
}

// Single-wave final reduction over 2048 float2 (16 KiB).
extern "C" __global__ void __launch_bounds__(64)
mtl_final(const float2* __restrict__ part, float* __restrict__ out) {
    const int lane = threadIdx.x;
    const float4* p4 = reinterpret_cast<const float4*>(part);  // 1024 float4
    float s = 0.0f, c = 0.0f;
    #pragma unroll
    for (int k = 0; k < 16; ++k) {
        const float4 v = p4[lane + (k << 6)];
        s += v.x + v.z;
        c += v.y + v.w;
    }
    #pragma unroll
    for (int off = 32; off > 0; off >>= 1) {
        s += __shfl_down(s, off);
        c += __shfl_down(c, off);
    }
    if (lane == 0) out[0] = s / fmaxf(c, 1.0f);
}

extern "C" void kernel_launch(void* const* d_in, const int* in_sizes, int n_in,
                              void* d_out, int out_size, void* d_ws, size_t ws_size,
                              hipStream_t stream) {
    const float* preds   = (const float*)d_in[0];
    const int*   labels  = (const int*)d_in[1];
    const float* weights = (const float*)d_in[2];
    float*       out     = (float*)d_out;

    float2* part = (float2*)d_ws;   // 2048 * 8 B = 16 KiB

    mtl_partial<<<NBLK, 256, 0, stream>>>(preds, labels, weights, part);
    mtl_final<<<1, 64, 0, stream>>>(part, out);
}